// Round 6
// baseline (381.720 us; speedup 1.0000x reference)
//
#include <hip/hip_runtime.h>

#define RAD   1
#define EPS_F 0.01f
#define LR_H  512
#define LR_W  512
#define HR_H  2048
#define HR_W  2048
#define NC    12   // N*C = 4*3

#define LR_PLANE (LR_H * LR_W)
#define HR_PLANE (HR_H * HR_W)
#define LR_TOTAL (NC * LR_PLANE)
#define HR_TOTAL (NC * HR_PLANE)

// ---- fused LR pass: stats -> A,b -> 3x3 box -> mA,mb, all in LDS ----
// One block = one 32x32 output tile. Halo x/y tile 36x36, A/b tile 34x34.
#define TILE 32
#define XT   (TILE + 4)   // 36
#define XSTR (XT + 1)     // 37 (odd stride: no bank conflicts)
#define AT   (TILE + 2)   // 34
#define ASTR (AT + 1)     // 35

__global__ void __launch_bounds__(256) k_fused_lr(
    const float* __restrict__ x, const float* __restrict__ y,
    float* __restrict__ mA, float* __restrict__ mb) {
    __shared__ float xs[XT * XSTR];
    __shared__ float ys[XT * XSTR];
    __shared__ float As[AT * ASTR];
    __shared__ float Bs[AT * ASTR];

    int bid = blockIdx.x;
    int p   = bid >> 8;          // plane (16x16 tiles per plane)
    int rem = bid & 255;
    int ty  = rem >> 4, tx = rem & 15;
    int oy  = ty * TILE, ox = tx * TILE;
    const float* xp = x + (size_t)p * LR_PLANE;
    const float* yp = y + (size_t)p * LR_PLANE;
    int tid = threadIdx.x;

    for (int i = tid; i < XT * XT; i += 256) {
        int r  = i / XT, c = i - r * XT;
        int gr = min(max(oy + r - 2, 0), LR_H - 1);
        int gc = min(max(ox + c - 2, 0), LR_W - 1);
        xs[r * XSTR + c] = xp[gr * LR_W + gc];
        ys[r * XSTR + c] = yp[gr * LR_W + gc];
    }
    __syncthreads();

    for (int i = tid; i < AT * AT; i += 256) {
        int k  = i / AT, c = i - k * AT;
        int q  = min(max(oy + k - 1, 0), LR_H - 1);
        int pc = min(max(ox + c - 1, 0), LR_W - 1);
        int rows[3] = { max(q - 1, 0)         - oy + 2,
                        q                     - oy + 2,
                        min(q + 1, LR_H - 1)  - oy + 2 };
        int cols[3] = { max(pc - 1, 0)        - ox + 2,
                        pc                    - ox + 2,
                        min(pc + 1, LR_W - 1) - ox + 2 };
        float sx = 0.f, sy = 0.f, sxy = 0.f, sxx = 0.f;
#pragma unroll
        for (int a = 0; a < 3; ++a) {
            int ro = rows[a] * XSTR;
#pragma unroll
            for (int b2 = 0; b2 < 3; ++b2) {
                float xv = xs[ro + cols[b2]];
                float yv = ys[ro + cols[b2]];
                sx  += xv;
                sy  += yv;
                sxy += xv * yv;
                sxx += xv * xv;
            }
        }
        const float inv9 = 1.0f / 9.0f;
        float mx  = sx * inv9;
        float my  = sy * inv9;
        float cov = sxy * inv9 - mx * my;
        float var = sxx * inv9 - mx * mx;
        float Av  = cov / (var + EPS_F);
        As[k * ASTR + c] = Av;
        Bs[k * ASTR + c] = my - Av * mx;
    }
    __syncthreads();

    float* mAp = mA + (size_t)p * LR_PLANE;
    float* mbp = mb + (size_t)p * LR_PLANE;
    for (int i = tid; i < TILE * TILE; i += 256) {
        int r = i >> 5, c = i & 31;
        float sA = 0.f, sB = 0.f;
#pragma unroll
        for (int a = 0; a < 3; ++a) {
            int ro = (r + a) * ASTR + c;
#pragma unroll
            for (int b2 = 0; b2 < 3; ++b2) {
                sA += As[ro + b2];
                sB += Bs[ro + b2];
            }
        }
        const float inv9 = 1.0f / 9.0f;
        mAp[(size_t)(oy + r) * LR_W + (ox + c)] = sA * inv9;
        mbp[(size_t)(oy + r) * LR_W + (ox + c)] = sB * inv9;
    }
}

// K3 v3: one block per (plane, 4 consecutive HR rows). The 4 rows share
// i0 in {R, R+1}, i1 <= R+2, so stage the 3 RAW mA/mb rows once (12.3 KB,
// -62% LR-side reads vs per-row staging), H-lerp them into 4 LDS rows
// (same FP order as before: H-lerp first, then W-lerp), then stream.
#define MW    513           // col j holds row[min(j,511)] (dup last col)

__global__ void __launch_bounds__(256) k_upsample_fuse4(
    const float* __restrict__ mA, const float* __restrict__ mb,
    const float* __restrict__ xhr, float* __restrict__ out) {
    __shared__ float rawA[3 * MW];
    __shared__ float rawB[3 * MW];
    __shared__ float hA[4 * MW];
    __shared__ float hB[4 * MW];

    const float scale = (float)(LR_H - 1) / (float)(HR_H - 1);

    // 6144 blocks; XCD-chunked bijective swizzle (6144 % 8 == 0):
    // adjacent row-groups share 2 of 3 staged LR rows -> same-L2 hits.
    int bid = blockIdx.x;
    int lin = (bid & 7) * 768 + (bid >> 3);
    int p   = lin >> 9;          // plane 0..11
    int rb  = lin & 511;         // row-group 0..511 (HR rows 4rb..4rb+3)
    int R   = (int)((float)(4 * rb) * scale);

    int tid = threadIdx.x;
    const float* Ap = mA + (size_t)p * LR_PLANE;
    const float* bp = mb + (size_t)p * LR_PLANE;

    // ---- Phase 1: stage raw mA/mb rows min(R+t, 511), cols 0..512 ----
#pragma unroll
    for (int t = 0; t < 3; ++t) {
        int rr = min(R + t, LR_H - 1);
        const float* ar = Ap + rr * LR_W;
        const float* br = bp + rr * LR_W;
        for (int c = tid; c < MW; c += 256) {
            int col = min(c, LR_W - 1);
            rawA[t * MW + c] = ar[col];
            rawB[t * MW + c] = br[col];
        }
    }
    __syncthreads();

    // ---- Phase 2: H-lerp into 4 per-row LDS buffers ----
#pragma unroll
    for (int k = 0; k < 4; ++k) {
        int i = 4 * rb + k;
        float ph = (float)i * scale;
        int   i0 = (int)ph;
        float th = ph - (float)i0;
        int   i1 = min(i0 + 1, LR_H - 1);
        float omh = 1.0f - th;
        int r0 = (i0 - R) * MW;   // i0-R in {0,1}
        int r1 = (i1 - R) * MW;   // i1-R in {1,2}
        for (int c = tid; c < MW; c += 256) {
            hA[k * MW + c] = rawA[r0 + c] * omh + rawA[r1 + c] * th;
            hB[k * MW + c] = rawB[r0 + c] * omh + rawB[r1 + c] * th;
        }
    }
    __syncthreads();

    // ---- Phase 3: stream 4 HR rows ----
    const size_t hrbase = (size_t)p * HR_PLANE;
#pragma unroll
    for (int k = 0; k < 4; ++k) {
        int i = 4 * rb + k;
        const float* xrow = xhr + hrbase + (size_t)i * HR_W;
        float*       orow = out + hrbase + (size_t)i * HR_W;
        const float* hAr = hA + k * MW;
        const float* hBr = hB + k * MW;
#pragma unroll
        for (int g = 0; g < 2; ++g) {
            int j = (tid + g * 256) * 4;
            const float4 xv = *(const float4*)(xrow + j);
            float xin[4] = {xv.x, xv.y, xv.z, xv.w};
            float r[4];
#pragma unroll
            for (int kk = 0; kk < 4; ++kk) {
                float pw = (float)(j + kk) * scale;
                int   j0 = (int)pw;
                float tw = pw - (float)j0;
                float omw = 1.0f - tw;
                float a  = hAr[j0] * omw + hAr[j0 + 1] * tw;
                float bb = hBr[j0] * omw + hBr[j0 + 1] * tw;
                float v  = a * xin[kk] + bb;
                r[kk] = fminf(fmaxf(v, 0.0f), 255.0f);
            }
            float4 o;
            o.x = r[0]; o.y = r[1]; o.z = r[2]; o.w = r[3];
            *(float4*)(orow + j) = o;
        }
    }
}

extern "C" void kernel_launch(void* const* d_in, const int* in_sizes, int n_in,
                              void* d_out, int out_size, void* d_ws, size_t ws_size,
                              hipStream_t stream) {
    const float* x_lr = (const float*)d_in[0];
    const float* y_lr = (const float*)d_in[1];
    const float* x_hr = (const float*)d_in[2];
    float* out = (float*)d_out;

    float* mA = (float*)d_ws;
    float* mb = mA + LR_TOTAL;

    {
        int threads = 256;
        int blocks = NC * 16 * 16;         // one block per 32x32 LR tile
        k_fused_lr<<<blocks, threads, 0, stream>>>(x_lr, y_lr, mA, mb);
    }
    {
        int threads = 256;
        int blocks = NC * (HR_H / 4);      // 6144: 4 HR rows per block
        k_upsample_fuse4<<<blocks, threads, 0, stream>>>(mA, mb, x_hr, out);
    }
}